// Round 8
// baseline (888.628 us; speedup 1.0000x reference)
//
#include <hip/hip_runtime.h>

// Problem constants (fixed by reference setup_inputs)
#define Bn 32
#define Cn 512
#define HWn 4096   // 64*64
#define Kn 256     // C/2

typedef float vfloat4 __attribute__((ext_vector_type(4)));

// ---------------------------------------------------------------------------
// Kernel 1 (fused): per-(b,c) mean over H*W + per-batch conv1d/sigmoid/topk.
// One wave per 16 KiB channel slice (64 lanes x 16 dwordx4 temporal loads,
// double accumulate, shfl_xor butterfly). Each wave publishes its mean with
// an AGENT-scope release store, then bumps the per-batch arrival counter.
// A batch has Cn=512 slices -> 512 waves; the LAST one (prev==511) flags its
// block, which then computes conv+sigmoid+rank for that batch with
// arithmetic bit-identical to the old standalone topk kernel.
// Dispatch-order independent: whichever wave is last does the work.
// (Round-7 bug: threshold was 127 — counted blocks, not waves.)
// ---------------------------------------------------------------------------
__global__ __launch_bounds__(256) void eca_mean_topk_kernel(
    const float* __restrict__ x, const float* __restrict__ w,
    float* __restrict__ y, int* __restrict__ idx, int* __restrict__ cnt) {
    __shared__ int last_flag;
    if (threadIdx.x == 0) last_flag = 0;
    __syncthreads();

    int slice = (blockIdx.x << 2) + (threadIdx.x >> 6);  // 4 waves/block
    int lane = threadIdx.x & 63;
    int b = slice >> 9;  // Cn = 512 slices per batch; all 4 waves same batch
    const vfloat4* p = (const vfloat4*)(x + (size_t)slice * HWn);
    double s = 0.0;
#pragma unroll
    for (int i = 0; i < 16; ++i) {
        vfloat4 v = p[lane + (i << 6)];
        s += ((double)v.x + (double)v.y) + ((double)v.z + (double)v.w);
    }
#pragma unroll
    for (int m = 32; m; m >>= 1) s += __shfl_xor(s, m, 64);

    if (lane == 0) {
        float mval = (float)(s * (1.0 / 4096.0));
        __hip_atomic_store(&y[slice], mval, __ATOMIC_RELEASE,
                           __HIP_MEMORY_SCOPE_AGENT);
        int prev = __hip_atomic_fetch_add(&cnt[b], 1, __ATOMIC_ACQ_REL,
                                          __HIP_MEMORY_SCOPE_AGENT);
        if (prev == Cn - 1) last_flag = 1;  // 512 waves per batch
    }
    __syncthreads();
    if (!last_flag) return;

    // ---- topk for batch b (256 threads, 2 channels each) ----
    __shared__ float ybuf[Cn];
    __shared__ float sc[Cn];
    for (int c = threadIdx.x; c < Cn; c += 256)
        ybuf[c] = __hip_atomic_load(&y[b * Cn + c], __ATOMIC_RELAXED,
                                    __HIP_MEMORY_SCOPE_AGENT);
    __syncthreads();

    float w0 = w[0], w1 = w[1], w2 = w[2];
    for (int c = threadIdx.x; c < Cn; c += 256) {
        float ym1 = (c == 0) ? 0.0f : ybuf[c - 1];
        float y0 = ybuf[c];
        float yp1 = (c == Cn - 1) ? 0.0f : ybuf[c + 1];
        float t = __fmul_rn(w0, ym1);
        t = __fadd_rn(t, __fmul_rn(w1, y0));
        t = __fadd_rn(t, __fmul_rn(w2, yp1));
        sc[c] = 1.0f / (1.0f + expf(-t));
    }
    __syncthreads();

    const vfloat4* sc4 = (const vfloat4*)sc;
    for (int c = threadIdx.x; c < Cn; c += 256) {
        float sig = sc[c];
        int rank = 0;
#pragma unroll 4
        for (int q = 0; q < Cn / 4; ++q) {
            vfloat4 o = sc4[q];  // broadcast-friendly LDS read
            int j = q << 2;
            rank += (o.x > sig || (o.x == sig && (j + 0) < c)) ? 1 : 0;
            rank += (o.y > sig || (o.y == sig && (j + 1) < c)) ? 1 : 0;
            rank += (o.z > sig || (o.z == sig && (j + 2) < c)) ? 1 : 0;
            rank += (o.w > sig || (o.w == sig && (j + 3) < c)) ? 1 : 0;
        }
        if (rank < Kn) idx[b * Kn + rank] = c;
    }
}

// ---------------------------------------------------------------------------
// Kernel 2: gather selected channel slices. One block per (b, rank) output
// slice; uniform index load, then coalesced float4 copy of 16 KB.
// Temporal loads (nt loads regressed -7us); NON-TEMPORAL stores (write-only
// output, never re-read; measured +2.7us).
// ---------------------------------------------------------------------------
__global__ __launch_bounds__(256) void eca_gather_kernel(
    const float* __restrict__ x, const int* __restrict__ idx,
    float* __restrict__ out) {
    int bj = blockIdx.x;  // b*Kn + j
    int b = bj >> 8;      // Kn == 256
    int c = idx[bj];
    const vfloat4* src = (const vfloat4*)(x + ((size_t)b * Cn + c) * HWn);
    vfloat4* dst = (vfloat4*)(out + (size_t)bj * HWn);
    int t = threadIdx.x;

    vfloat4 v[4];
#pragma unroll
    for (int i = 0; i < 4; ++i) v[i] = src[t + i * 256];
#pragma unroll
    for (int i = 0; i < 4; ++i)
        __builtin_nontemporal_store(v[i], &dst[t + i * 256]);
}

extern "C" void kernel_launch(void* const* d_in, const int* in_sizes, int n_in,
                              void* d_out, int out_size, void* d_ws,
                              size_t ws_size, hipStream_t stream) {
    const float* x = (const float*)d_in[0];
    const float* w = (const float*)d_in[1];
    float* out = (float*)d_out;

    float* y = (float*)d_ws;                                  // 64 KiB
    int* idx = (int*)((char*)d_ws + Bn * Cn * sizeof(float)); // 32 KiB
    int* cnt = (int*)((char*)d_ws + Bn * Cn * sizeof(float)
                      + Bn * Kn * sizeof(int));               // 128 B

    // per-call zeroing of the wave-arrival counters (graph-capturable)
    hipMemsetAsync(cnt, 0, Bn * sizeof(int), stream);

    eca_mean_topk_kernel<<<(Bn * Cn) / 4, 256, 0, stream>>>(x, w, y, idx, cnt);
    eca_gather_kernel<<<Bn * Kn, 256, 0, stream>>>(x, idx, out);
}

// Round 9
// 98.711 us; speedup vs baseline: 9.0024x; 9.0024x over previous
//
#include <hip/hip_runtime.h>

// Problem constants (fixed by reference setup_inputs)
#define Bn 32
#define Cn 512
#define HWn 4096   // 64*64
#define Kn 256     // C/2

typedef float vfloat4 __attribute__((ext_vector_type(4)));

// ---------------------------------------------------------------------------
// Kernel 1: per-(b,c) mean over H*W. One wave per 16 KiB channel slice:
// 64 lanes x 16 dwordx4 temporal loads, double accumulate, shfl_xor
// butterfly. Double keeps the fp32-rounded result order-independent
// (top-k rank depends on it). [Round-8 lesson: NO agent-scope ordered
// atomics in streaming kernels — acquire's buffer_inv nukes the XCD L2.]
// ---------------------------------------------------------------------------
__global__ __launch_bounds__(256) void eca_mean_kernel(
    const float* __restrict__ x, float* __restrict__ y) {
    int slice = (blockIdx.x << 2) + (threadIdx.x >> 6);
    int lane = threadIdx.x & 63;
    const vfloat4* p = (const vfloat4*)(x + (size_t)slice * HWn);
    double s = 0.0;
#pragma unroll
    for (int i = 0; i < 16; ++i) {
        vfloat4 v = p[lane + (i << 6)];
        s += ((double)v.x + (double)v.y) + ((double)v.z + (double)v.w);
    }
#pragma unroll
    for (int m = 32; m; m >>= 1) s += __shfl_xor(s, m, 64);
    if (lane == 0) y[slice] = (float)(s * (1.0 / 4096.0));
}

// ---------------------------------------------------------------------------
// Kernel 2: conv1d(pad=1) + sigmoid + top-k rank per batch. One block per
// batch, 512 threads (one per channel). Rank-by-counting reproduces
// lax.top_k's descending order with stable (lower-index-first) ties.
// Conv replicated as numpy does it: separate fp32 mul/adds, left-to-right,
// no FMA contraction. Rank loop reads LDS as float4 broadcasts.
// ---------------------------------------------------------------------------
__global__ __launch_bounds__(Cn) void eca_topk_kernel(
    const float* __restrict__ y, const float* __restrict__ w,
    int* __restrict__ idx) {
    int b = blockIdx.x;
    int c = threadIdx.x;  // 0 .. Cn-1
    __shared__ float sc[Cn];

    float w0 = w[0], w1 = w[1], w2 = w[2];
    float ym1 = (c == 0) ? 0.0f : y[b * Cn + c - 1];
    float y0 = y[b * Cn + c];
    float yp1 = (c == Cn - 1) ? 0.0f : y[b * Cn + c + 1];

    float s = __fmul_rn(w0, ym1);
    s = __fadd_rn(s, __fmul_rn(w1, y0));
    s = __fadd_rn(s, __fmul_rn(w2, yp1));
    float sig = 1.0f / (1.0f + expf(-s));

    sc[c] = sig;
    __syncthreads();

    const vfloat4* sc4 = (const vfloat4*)sc;
    int rank = 0;
#pragma unroll 4
    for (int q = 0; q < Cn / 4; ++q) {
        vfloat4 o = sc4[q];  // same address across lanes -> LDS broadcast
        int j = q << 2;
        rank += (o.x > sig || (o.x == sig && (j + 0) < c)) ? 1 : 0;
        rank += (o.y > sig || (o.y == sig && (j + 1) < c)) ? 1 : 0;
        rank += (o.z > sig || (o.z == sig && (j + 2) < c)) ? 1 : 0;
        rank += (o.w > sig || (o.w == sig && (j + 3) < c)) ? 1 : 0;
    }
    if (rank < Kn) idx[b * Kn + rank] = c;
}

// ---------------------------------------------------------------------------
// Kernel 3: gather selected channel slices. ONE WAVE per 16 KiB output
// slice (like the mean kernel): 64 lanes x 16 dwordx4 loads all issued
// before the stores -> 16 outstanding loads/lane, no barriers, 2048 blocks.
// Temporal loads (nt loads regressed -7us); NON-TEMPORAL stores
// (write-only output, never re-read; measured +2.7us).
// ---------------------------------------------------------------------------
__global__ __launch_bounds__(256) void eca_gather_kernel(
    const float* __restrict__ x, const int* __restrict__ idx,
    float* __restrict__ out) {
    int bj = (blockIdx.x << 2) + (threadIdx.x >> 6);  // slice id 0..8191
    int lane = threadIdx.x & 63;
    int b = bj >> 8;  // Kn == 256
    int c = idx[bj];
    const vfloat4* src = (const vfloat4*)(x + ((size_t)b * Cn + c) * HWn);
    vfloat4* dst = (vfloat4*)(out + (size_t)bj * HWn);

    vfloat4 v[16];
#pragma unroll
    for (int i = 0; i < 16; ++i) v[i] = src[lane + (i << 6)];
#pragma unroll
    for (int i = 0; i < 16; ++i)
        __builtin_nontemporal_store(v[i], &dst[lane + (i << 6)]);
}

extern "C" void kernel_launch(void* const* d_in, const int* in_sizes, int n_in,
                              void* d_out, int out_size, void* d_ws,
                              size_t ws_size, hipStream_t stream) {
    const float* x = (const float*)d_in[0];
    const float* w = (const float*)d_in[1];
    float* out = (float*)d_out;

    float* y = (float*)d_ws;                                  // Bn*Cn floats
    int* idx = (int*)((char*)d_ws + Bn * Cn * sizeof(float)); // Bn*Kn ints

    eca_mean_kernel<<<(Bn * Cn) / 4, 256, 0, stream>>>(x, y);
    eca_topk_kernel<<<Bn, Cn, 0, stream>>>(y, w, idx);
    eca_gather_kernel<<<(Bn * Kn) / 4, 256, 0, stream>>>(x, idx, out);
}

// Round 10
// 98.011 us; speedup vs baseline: 9.0666x; 1.0071x over previous
//
#include <hip/hip_runtime.h>

// Problem constants (fixed by reference setup_inputs)
#define Bn 32
#define Cn 512
#define HWn 4096   // 64*64
#define Kn 256     // C/2

typedef float vfloat4 __attribute__((ext_vector_type(4)));

// ---------------------------------------------------------------------------
// Kernel 1: per-(b,c) mean over H*W. One wave per 16 KiB channel slice:
// 64 lanes x 16 dwordx4 temporal loads, double accumulate, shfl_xor
// butterfly. Double keeps the fp32-rounded result order-independent
// (top-k rank depends on it). Measured best: 98.1 us total (round 4).
// [Round-5 lesson: nt loads -7us. Round-8 lesson: NO agent-scope ordered
// atomics in streaming kernels — acquire's buffer_inv nukes the XCD L2.]
// ---------------------------------------------------------------------------
__global__ __launch_bounds__(256) void eca_mean_kernel(
    const float* __restrict__ x, float* __restrict__ y) {
    int slice = (blockIdx.x << 2) + (threadIdx.x >> 6);
    int lane = threadIdx.x & 63;
    const vfloat4* p = (const vfloat4*)(x + (size_t)slice * HWn);
    double s = 0.0;
#pragma unroll
    for (int i = 0; i < 16; ++i) {
        vfloat4 v = p[lane + (i << 6)];
        s += ((double)v.x + (double)v.y) + ((double)v.z + (double)v.w);
    }
#pragma unroll
    for (int m = 32; m; m >>= 1) s += __shfl_xor(s, m, 64);
    if (lane == 0) y[slice] = (float)(s * (1.0 / 4096.0));
}

// ---------------------------------------------------------------------------
// Kernel 2: conv1d(pad=1) + sigmoid + top-k rank per batch. One block per
// batch, 512 threads (one per channel). Rank-by-counting reproduces
// lax.top_k's descending order with stable (lower-index-first) ties.
// Conv replicated as numpy does it: separate fp32 mul/adds, left-to-right,
// no FMA contraction. Rank loop reads LDS as float4 broadcasts.
// ---------------------------------------------------------------------------
__global__ __launch_bounds__(Cn) void eca_topk_kernel(
    const float* __restrict__ y, const float* __restrict__ w,
    int* __restrict__ idx) {
    int b = blockIdx.x;
    int c = threadIdx.x;  // 0 .. Cn-1
    __shared__ float sc[Cn];

    float w0 = w[0], w1 = w[1], w2 = w[2];
    float ym1 = (c == 0) ? 0.0f : y[b * Cn + c - 1];
    float y0 = y[b * Cn + c];
    float yp1 = (c == Cn - 1) ? 0.0f : y[b * Cn + c + 1];

    float s = __fmul_rn(w0, ym1);
    s = __fadd_rn(s, __fmul_rn(w1, y0));
    s = __fadd_rn(s, __fmul_rn(w2, yp1));
    float sig = 1.0f / (1.0f + expf(-s));

    sc[c] = sig;
    __syncthreads();

    const vfloat4* sc4 = (const vfloat4*)sc;
    int rank = 0;
#pragma unroll 4
    for (int q = 0; q < Cn / 4; ++q) {
        vfloat4 o = sc4[q];  // same address across lanes -> LDS broadcast
        int j = q << 2;
        rank += (o.x > sig || (o.x == sig && (j + 0) < c)) ? 1 : 0;
        rank += (o.y > sig || (o.y == sig && (j + 1) < c)) ? 1 : 0;
        rank += (o.z > sig || (o.z == sig && (j + 2) < c)) ? 1 : 0;
        rank += (o.w > sig || (o.w == sig && (j + 3) < c)) ? 1 : 0;
    }
    if (rank < Kn) idx[b * Kn + rank] = c;
}

// ---------------------------------------------------------------------------
// Kernel 3: gather selected channel slices. One block per (b, rank) output
// slice; uniform index load, then coalesced float4 copy of 16 KB.
// Temporal loads (nt loads regressed -7us); NON-TEMPORAL stores (write-only
// output, never re-read; measured +2.7us). Block-per-slice measured best
// (98.1/98.2 vs 98.7 wave-per-slice, rounds 4/6/9).
// ---------------------------------------------------------------------------
__global__ __launch_bounds__(256) void eca_gather_kernel(
    const float* __restrict__ x, const int* __restrict__ idx,
    float* __restrict__ out) {
    int bj = blockIdx.x;  // b*Kn + j
    int b = bj >> 8;      // Kn == 256
    int c = idx[bj];
    const vfloat4* src = (const vfloat4*)(x + ((size_t)b * Cn + c) * HWn);
    vfloat4* dst = (vfloat4*)(out + (size_t)bj * HWn);
    int t = threadIdx.x;

    vfloat4 v[4];
#pragma unroll
    for (int i = 0; i < 4; ++i) v[i] = src[t + i * 256];
#pragma unroll
    for (int i = 0; i < 4; ++i)
        __builtin_nontemporal_store(v[i], &dst[t + i * 256]);
}

extern "C" void kernel_launch(void* const* d_in, const int* in_sizes, int n_in,
                              void* d_out, int out_size, void* d_ws,
                              size_t ws_size, hipStream_t stream) {
    const float* x = (const float*)d_in[0];
    const float* w = (const float*)d_in[1];
    float* out = (float*)d_out;

    float* y = (float*)d_ws;                                  // Bn*Cn floats
    int* idx = (int*)((char*)d_ws + Bn * Cn * sizeof(float)); // Bn*Kn ints

    eca_mean_kernel<<<(Bn * Cn) / 4, 256, 0, stream>>>(x, y);
    eca_topk_kernel<<<Bn, Cn, 0, stream>>>(y, w, idx);
    eca_gather_kernel<<<Bn * Kn, 256, 0, stream>>>(x, idx, out);
}